// Round 7
// baseline (68.448 us; speedup 1.0000x reference)
//
#include <hip/hip_runtime.h>

#define IN_CH 64
#define OUT_CH 128
#define HW 128
#define KTAPS 9
#define ROWB 16384             // bytes per staged row image: 128 w * 64 ic * 2B

typedef __bf16 bf16x8 __attribute__((ext_vector_type(8)));
typedef float f32x16 __attribute__((ext_vector_type(16)));
typedef float f32x4 __attribute__((ext_vector_type(4)));

// fp32 -> bf16 round-to-nearest-even (data has no NaN/Inf)
__device__ __forceinline__ unsigned f2bf(float f) {
    unsigned u = __builtin_bit_cast(unsigned, f);
    return (u + 0x7FFFu + ((u >> 16) & 1u)) >> 16;
}

// 16B-granule XOR swizzle keyed by row (3 bits -> byte-addr bits 4..6).
// Applied on B's LDS writes/reads: spreads a wave's 32 stride-128B row
// accesses over 8 bank-groups -> conflict-free ds_read_b128.
__device__ __forceinline__ int swz(int r) { return ((r ^ (r >> 3)) & 7) << 4; }

// W (OIHW fp32) -> Wl in wave-fragment order:
// 16B chunk index = (p*9 + t)*512 + (m*4 + ks)*64 + lane
// Chunk content: 8 bf16 of A[oc = p*64+m*32+(lane&31)][ic = ks*16+(lane>>5)*8 .. +8].
// A wave's per-tap A-fragment loads are 8 lane-contiguous 1KB dwordx4 loads.
__global__ void wprep_kernel(const float* __restrict__ W, unsigned short* __restrict__ Wl) {
    int i = blockIdx.x * blockDim.x + threadIdx.x;   // 73728 bf16 elements
    if (i >= OUT_CH * IN_CH * KTAPS) return;
    int p  = i / 36864;
    int r  = i % 36864;
    int t  = r >> 12;          // 0..8
    int r2 = r & 4095;
    int m  = r2 >> 11;
    int ks = (r2 >> 9) & 3;
    int l  = (r2 >> 3) & 63;
    int e  = r2 & 7;
    int oc = p * 64 + m * 32 + (l & 31);
    int ic = ks * 16 + (l >> 5) * 8 + e;
    int kh = t / 3, kw = t % 3;
    Wl[i] = (unsigned short)f2bf(W[((oc * IN_CH + ic) * 3 + kh) * 3 + kw]);
}

// Fused conv: B (3 x-rows) converted+staged to LDS once (single barrier);
// K-loop is barrier-free with BOTH operands double-buffered in registers,
// prefetched one tap ahead (A: 8 global dwordx4 from L2-resident Wl;
// B: 8 swizzled ds_read_b128). 16 MFMAs per tap hide both latencies.
__global__ __launch_bounds__(256, 2) void conv_kernel_f(
    const float* __restrict__ x, const unsigned short* __restrict__ Wl,
    const float* __restrict__ bias, float* __restrict__ y)
{
    __shared__ __align__(16) unsigned char xsB[3 * ROWB];   // 48 KiB

    int bid = blockIdx.x;
    int sb  = (bid & 7) * 256 + (bid >> 3);   // XCD-contiguous h ranges (bijective: 2048 = 8*256)
    int n = sb >> 7, h = sb & 127;
    int tid = threadIdx.x;
    int wid = tid >> 6, lane = tid & 63;
    int wr = wid >> 1, wc = wid & 1;
    int l31 = lane & 31, lhi = lane >> 5;

    // A chunk pointer (16B units): wave half wr, per-lane chunk.
    const bf16x8* Ab = reinterpret_cast<const bf16x8*>(Wl) + wr * (9 * 512) + lane;

    // Issue tap-0 A-frag loads first: in flight during the whole staging phase.
    bf16x8 aBuf[2][8];
    #pragma unroll
    for (int j = 0; j < 8; ++j) aBuf[0][j] = Ab[j * 64];

    // ---- stage 3 B-rows (h-8, h, h+8) from fp32 x: convert + swizzled write ----
    #pragma unroll
    for (int it = 0; it < 3; ++it) {
        int q   = it * 256 + tid;    // 0..767: (kh, ic8, w4)
        int w4  = q & 31;
        int ic8 = (q >> 5) & 7;
        int kh  = q >> 8;
        int srow = (h + kh * 8 + 120) & 127;   // h-8, h, h+8 (mod 128)
        const float* xp = x + (((n * IN_CH + ic8 * 8) * HW + srow) * HW + w4 * 4);
        f32x4 v[8];
        #pragma unroll
        for (int j = 0; j < 8; ++j)
            v[j] = *reinterpret_cast<const f32x4*>(xp + j * (HW * HW));
        #pragma unroll
        for (int j2 = 0; j2 < 4; ++j2) {
            int w = w4 * 4 + j2;
            uint4 pk;
            pk.x = f2bf(v[0][j2]) | (f2bf(v[1][j2]) << 16);
            pk.y = f2bf(v[2][j2]) | (f2bf(v[3][j2]) << 16);
            pk.z = f2bf(v[4][j2]) | (f2bf(v[5][j2]) << 16);
            pk.w = f2bf(v[6][j2]) | (f2bf(v[7][j2]) << 16);
            *reinterpret_cast<uint4*>(xsB + kh * ROWB + ((w * 128 + ic8 * 16) ^ swz(w))) = pk;
        }
    }
    __syncthreads();   // the ONLY barrier

    // B-frag read helper addresses per tap are computed statically in the unrolled loop.
    f32x16 acc[2][2];
    #pragma unroll
    for (int a = 0; a < 2; ++a)
        #pragma unroll
        for (int bq = 0; bq < 2; ++bq)
            #pragma unroll
            for (int r = 0; r < 16; ++r) acc[a][bq][r] = 0.0f;

    bf16x8 bBuf[2][8];
    // preload tap-0 B-frags
    {
        int xc0 = (wc * 64 + l31 + 8 * 0 - 8) & 127;   // kw=0
        int xc1 = (xc0 + 32) & 127;
        int b0base = 0 * ROWB + xc0 * 128 + lhi * 16, s0 = swz(xc0);
        int b1base = 0 * ROWB + xc1 * 128 + lhi * 16, s1 = swz(xc1);
        #pragma unroll
        for (int ks = 0; ks < 4; ++ks) {
            bBuf[0][ks]     = *reinterpret_cast<const bf16x8*>(xsB + ((b0base + ks * 32) ^ s0));
            bBuf[0][4 + ks] = *reinterpret_cast<const bf16x8*>(xsB + ((b1base + ks * 32) ^ s1));
        }
    }

    #pragma unroll
    for (int t = 0; t < 9; ++t) {
        // prefetch tap t+1's operands (fly under this tap's MFMAs)
        if (t < 8) {
            int tn = t + 1;
            #pragma unroll
            for (int j = 0; j < 8; ++j)
                aBuf[tn & 1][j] = Ab[tn * 512 + j * 64];
            int kh = tn / 3, kw = tn % 3;
            int xc0 = (wc * 64 + l31 + 8 * kw - 8) & 127;
            int xc1 = (xc0 + 32) & 127;
            int b0base = kh * ROWB + xc0 * 128 + lhi * 16, s0 = swz(xc0);
            int b1base = kh * ROWB + xc1 * 128 + lhi * 16, s1 = swz(xc1);
            #pragma unroll
            for (int ks = 0; ks < 4; ++ks) {
                bBuf[tn & 1][ks]     = *reinterpret_cast<const bf16x8*>(xsB + ((b0base + ks * 32) ^ s0));
                bBuf[tn & 1][4 + ks] = *reinterpret_cast<const bf16x8*>(xsB + ((b1base + ks * 32) ^ s1));
            }
        }
        // 16 MFMAs on tap t's registers (setprio: favor MFMA-phase waves)
        __builtin_amdgcn_s_setprio(1);
        #pragma unroll
        for (int ks = 0; ks < 4; ++ks) {
            bf16x8 a0 = aBuf[t & 1][ks];
            bf16x8 a1 = aBuf[t & 1][4 + ks];
            bf16x8 b0 = bBuf[t & 1][ks];
            bf16x8 b1 = bBuf[t & 1][4 + ks];
            acc[0][0] = __builtin_amdgcn_mfma_f32_32x32x16_bf16(a0, b0, acc[0][0], 0, 0, 0);
            acc[0][1] = __builtin_amdgcn_mfma_f32_32x32x16_bf16(a0, b1, acc[0][1], 0, 0, 0);
            acc[1][0] = __builtin_amdgcn_mfma_f32_32x32x16_bf16(a1, b0, acc[1][0], 0, 0, 0);
            acc[1][1] = __builtin_amdgcn_mfma_f32_32x32x16_bf16(a1, b1, acc[1][1], 0, 0, 0);
        }
        __builtin_amdgcn_s_setprio(0);
    }

    // ---- epilogue: bias + nontemporal store (y is write-once; keep L2 for A) ----
    // D: col=l31(w), row=(reg&3)+8*(reg>>2)+4*lhi
    int outbase = (n * OUT_CH) * HW * HW + h * HW;
    #pragma unroll
    for (int mi = 0; mi < 2; ++mi) {
        #pragma unroll
        for (int ni = 0; ni < 2; ++ni) {
            int wcol = wc * 64 + ni * 32 + l31;
            #pragma unroll
            for (int reg = 0; reg < 16; ++reg) {
                int oc = wr * 64 + mi * 32 + (reg & 3) + 8 * (reg >> 2) + 4 * lhi;
                __builtin_nontemporal_store(acc[mi][ni][reg] + bias[oc],
                                            &y[outbase + oc * HW * HW + wcol]);
            }
        }
    }
}

extern "C" void kernel_launch(void* const* d_in, const int* in_sizes, int n_in,
                              void* d_out, int out_size, void* d_ws, size_t ws_size,
                              hipStream_t stream) {
    const float* x = (const float*)d_in[0];
    const float* W = (const float*)d_in[1];
    const float* b = (const float*)d_in[2];
    float* y = (float*)d_out;

    unsigned short* Wl = (unsigned short*)d_ws;   // 147456 B

    hipLaunchKernelGGL(wprep_kernel, dim3((OUT_CH * IN_CH * KTAPS + 255) / 256), dim3(256), 0, stream, W, Wl);
    hipLaunchKernelGGL(conv_kernel_f, dim3(16 * HW), dim3(256), 0, stream, x, Wl, b, y);
}

// Round 9
// 64.015 us; speedup vs baseline: 1.0692x; 1.0692x over previous
//
#include <hip/hip_runtime.h>

#define IN_CH 64
#define OUT_CH 128
#define HW 128
#define KTAPS 9
#define ROWB 16384             // bytes per staged row image: 128 w * 64 ic * 2B

typedef __bf16 bf16x8 __attribute__((ext_vector_type(8)));
typedef float f32x16 __attribute__((ext_vector_type(16)));
typedef float f32x4 __attribute__((ext_vector_type(4)));

// fp32 -> bf16 round-to-nearest-even (data has no NaN/Inf)
__device__ __forceinline__ unsigned f2bf(float f) {
    unsigned u = __builtin_bit_cast(unsigned, f);
    return (u + 0x7FFFu + ((u >> 16) & 1u)) >> 16;
}

// 16B-granule XOR swizzle keyed by row (3 bits -> byte-addr bits 4..6).
// Applied on B's LDS writes/reads: spreads a wave's 32 stride-128B row
// accesses over 8 bank-groups -> conflict-free ds_read_b128.
__device__ __forceinline__ int swz(int r) { return ((r ^ (r >> 3)) & 7) << 4; }

// W (OIHW fp32) -> Wl in wave-fragment order (PROVEN since R6):
// 16B chunk index = (p*9 + t)*512 + (m*4 + ks)*64 + lane
// Chunk content: 8 bf16 of A[oc = p*64+m*32+(lane&31)][ic = ks*16+(lane>>5)*8 .. +8].
__global__ void wprep_kernel(const float* __restrict__ W, unsigned short* __restrict__ Wl) {
    int i = blockIdx.x * blockDim.x + threadIdx.x;   // 73728 bf16 elements
    if (i >= OUT_CH * IN_CH * KTAPS) return;
    int p  = i / 36864;
    int r  = i % 36864;
    int t  = r >> 12;          // 0..8
    int r2 = r & 4095;
    int m  = r2 >> 11;
    int ks = (r2 >> 9) & 3;
    int l  = (r2 >> 3) & 63;
    int e  = r2 & 7;
    int oc = p * 64 + m * 32 + (l & 31);
    int ic = ks * 16 + (l >> 5) * 8 + e;
    int kh = t / 3, kw = t % 3;
    Wl[i] = (unsigned short)f2bf(W[((oc * IN_CH + ic) * 3 + kh) * 3 + kw]);
}

// Fused conv, 512 threads / 8 waves per (n,h) block. Each wave computes a
// 32oc x 64w tile (acc = 32 VGPR) -> fits 85-reg cap -> 3 blocks/CU =
// 6 waves/SIMD of TLP to hide A-from-L2 and LDS latency (R6/R7 A/B showed
// TLP beats hand-ILP here). Staging + swizzle + Wl layout proven R2-R7.
__global__ __launch_bounds__(512, 6) void conv_kernel_f(
    const float* __restrict__ x, const unsigned short* __restrict__ Wl,
    const float* __restrict__ bias, float* __restrict__ y)
{
    __shared__ __align__(16) unsigned char xsB[3 * ROWB];   // 48 KiB -> 3 blocks/CU

    int bid = blockIdx.x;
    int sb  = (bid & 7) * 256 + (bid >> 3);   // XCD-contiguous h ranges (bijective: 2048 = 8*256)
    int n = sb >> 7, h = sb & 127;
    int tid = threadIdx.x;
    int wid = tid >> 6, lane = tid & 63;

    // ---- stage 3 B-rows (h-8, h, h+8) from fp32 x: convert + swizzled write ----
    // 768 groups (kh, ic8, w4); threads 0..255 take a second group.
    for (int q = tid; q < 768; q += 512) {
        int w4  = q & 31;
        int ic8 = (q >> 5) & 7;
        int kh  = q >> 8;
        int srow = (h + kh * 8 + 120) & 127;   // h-8, h, h+8 (mod 128)
        const float* xp = x + (((n * IN_CH + ic8 * 8) * HW + srow) * HW + w4 * 4);
        f32x4 v[8];
        #pragma unroll
        for (int j = 0; j < 8; ++j)
            v[j] = *reinterpret_cast<const f32x4*>(xp + j * (HW * HW));
        #pragma unroll
        for (int j2 = 0; j2 < 4; ++j2) {
            int w = w4 * 4 + j2;
            uint4 pk;
            pk.x = f2bf(v[0][j2]) | (f2bf(v[1][j2]) << 16);
            pk.y = f2bf(v[2][j2]) | (f2bf(v[3][j2]) << 16);
            pk.z = f2bf(v[4][j2]) | (f2bf(v[5][j2]) << 16);
            pk.w = f2bf(v[6][j2]) | (f2bf(v[7][j2]) << 16);
            *reinterpret_cast<uint4*>(xsB + kh * ROWB + ((w * 128 + ic8 * 16) ^ swz(w))) = pk;
        }
    }
    __syncthreads();   // the ONLY barrier

    // wave roles: wr = oc quarter (32 rows), wc = w half (64 cols)
    int wr = wid >> 1, wc = wid & 1;
    int l31 = lane & 31, lhi = lane >> 5;
    int p = wr >> 1, m = wr & 1;

    // A chunk pointer (16B units): proven fragment order, quarter-selected.
    const bf16x8* Ab = reinterpret_cast<const bf16x8*>(Wl)
                     + p * (9 * 512) + m * 256 + lane;

    f32x16 acc[2];
    #pragma unroll
    for (int bq = 0; bq < 2; ++bq)
        #pragma unroll
        for (int r = 0; r < 16; ++r) acc[bq][r] = 0.0f;

    #pragma unroll
    for (int t = 0; t < 9; ++t) {
        // per-tap A fragments: 4 lane-contiguous 1KB dwordx4 loads from L2-resident Wl
        bf16x8 aCur[4];
        #pragma unroll
        for (int ks = 0; ks < 4; ++ks) aCur[ks] = Ab[t * 512 + ks * 64];

        int kh = t / 3, kw = t % 3;
        int xc0 = (wc * 64 + l31 + 8 * kw - 8) & 127;   // circular column
        int xc1 = (xc0 + 32) & 127;
        int b0base = kh * ROWB + xc0 * 128 + lhi * 16, s0 = swz(xc0);
        int b1base = kh * ROWB + xc1 * 128 + lhi * 16, s1 = swz(xc1);
        #pragma unroll
        for (int ks = 0; ks < 4; ++ks) {   // K=16 per MFMA, 64 ic per tap
            bf16x8 b0 = *reinterpret_cast<const bf16x8*>(xsB + ((b0base + ks * 32) ^ s0));
            bf16x8 b1 = *reinterpret_cast<const bf16x8*>(xsB + ((b1base + ks * 32) ^ s1));
            acc[0] = __builtin_amdgcn_mfma_f32_32x32x16_bf16(aCur[ks], b0, acc[0], 0, 0, 0);
            acc[1] = __builtin_amdgcn_mfma_f32_32x32x16_bf16(aCur[ks], b1, acc[1], 0, 0, 0);
        }
    }

    // ---- epilogue: bias + store. D: col=l31(w), row=(reg&3)+8*(reg>>2)+4*lhi ----
    int outbase = (n * OUT_CH) * HW * HW + h * HW;
    #pragma unroll
    for (int bq = 0; bq < 2; ++bq) {
        int wcol = wc * 64 + bq * 32 + l31;
        #pragma unroll
        for (int reg = 0; reg < 16; ++reg) {
            int oc = wr * 32 + (reg & 3) + 8 * (reg >> 2) + 4 * lhi;
            y[outbase + oc * HW * HW + wcol] = acc[bq][reg] + bias[oc];
        }
    }
}

extern "C" void kernel_launch(void* const* d_in, const int* in_sizes, int n_in,
                              void* d_out, int out_size, void* d_ws, size_t ws_size,
                              hipStream_t stream) {
    const float* x = (const float*)d_in[0];
    const float* W = (const float*)d_in[1];
    const float* b = (const float*)d_in[2];
    float* y = (float*)d_out;

    unsigned short* Wl = (unsigned short*)d_ws;   // 147456 B

    hipLaunchKernelGGL(wprep_kernel, dim3((OUT_CH * IN_CH * KTAPS + 255) / 256), dim3(256), 0, stream, W, Wl);
    hipLaunchKernelGGL(conv_kernel_f, dim3(16 * HW), dim3(512), 0, stream, x, Wl, b, y);
}

// Round 10
// 63.693 us; speedup vs baseline: 1.0747x; 1.0051x over previous
//
#include <hip/hip_runtime.h>

#define IN_CH 64
#define OUT_CH 128
#define HW 128
#define KTAPS 9
#define ROWB 16384             // bytes per staged row image: 128 w * 64 ic * 2B

typedef __bf16 bf16x8 __attribute__((ext_vector_type(8)));
typedef float f32x16 __attribute__((ext_vector_type(16)));
typedef float f32x4 __attribute__((ext_vector_type(4)));

// fp32 -> bf16 round-to-nearest-even (data has no NaN/Inf) — host-side/prep use
__device__ __forceinline__ unsigned f2bf(float f) {
    unsigned u = __builtin_bit_cast(unsigned, f);
    return (u + 0x7FFFu + ((u >> 16) & 1u)) >> 16;
}

// HW packed f32x2 -> bf16x2 (RNE), 1 instruction (no builtin on gfx950)
__device__ __forceinline__ unsigned cvt_pk_bf16(float lo, float hi) {
    unsigned r;
    asm("v_cvt_pk_bf16_f32 %0, %1, %2" : "=v"(r) : "v"(lo), "v"(hi));
    return r;   // [15:0]=bf16(lo), [31:16]=bf16(hi)
}

// 16B-granule XOR swizzle keyed by row (3 bits -> byte-addr bits 4..6).
// Applied on B's LDS writes/reads: spreads a wave's 32 stride-128B row
// accesses over 8 bank-groups -> conflict-free ds_read_b128.
__device__ __forceinline__ int swz(int r) { return ((r ^ (r >> 3)) & 7) << 4; }

// W (OIHW fp32) -> Wl in wave-fragment order (PROVEN since R6):
// 16B chunk index = (p*9 + t)*512 + (m*4 + ks)*64 + lane
// Chunk content: 8 bf16 of A[oc = p*64+m*32+(lane&31)][ic = ks*16+(lane>>5)*8 .. +8].
__global__ void wprep_kernel(const float* __restrict__ W, unsigned short* __restrict__ Wl) {
    int i = blockIdx.x * blockDim.x + threadIdx.x;   // 73728 bf16 elements
    if (i >= OUT_CH * IN_CH * KTAPS) return;
    int p  = i / 36864;
    int r  = i % 36864;
    int t  = r >> 12;          // 0..8
    int r2 = r & 4095;
    int m  = r2 >> 11;
    int ks = (r2 >> 9) & 3;
    int l  = (r2 >> 3) & 63;
    int e  = r2 & 7;
    int oc = p * 64 + m * 32 + (l & 31);
    int ic = ks * 16 + (l >> 5) * 8 + e;
    int kh = t / 3, kw = t % 3;
    Wl[i] = (unsigned short)f2bf(W[((oc * IN_CH + ic) * 3 + kh) * 3 + kw]);
}

// Fused conv, 512 threads / 8 waves per (n,h) block; each wave a 32oc x 64w
// tile (acc 32 VGPR) -> fits (512,6) cap -> 3 blocks/CU = 6 waves/SIMD TLP.
// Staging: perfectly balanced 3 quarter-groups/thread, HW cvt_pk conversion.
__global__ __launch_bounds__(512, 6) void conv_kernel_f(
    const float* __restrict__ x, const unsigned short* __restrict__ Wl,
    const float* __restrict__ bias, float* __restrict__ y)
{
    __shared__ __align__(16) unsigned char xsB[3 * ROWB];   // 48 KiB -> 3 blocks/CU

    int bid = blockIdx.x;
    int sb  = (bid & 7) * 256 + (bid >> 3);   // XCD-contiguous h ranges (bijective: 2048 = 8*256)
    int n = sb >> 7, h = sb & 127;
    int tid = threadIdx.x;
    int wid = tid >> 6, lane = tid & 63;

    // ---- stage 3 B-rows (h-8, h, h+8): 1536 quarter-groups (kh, ic4, w4),
    //      exactly 3 per thread; per group 4 float4 loads -> 8 cvt_pk -> 4 b64 writes.
    #pragma unroll
    for (int g = 0; g < 3; ++g) {
        int q   = g * 512 + tid;     // 0..1535
        int w4  = q & 31;
        int ic4 = (q >> 5) & 15;
        int kh  = q >> 9;
        int srow = (h + kh * 8 + 120) & 127;   // h-8, h, h+8 (mod 128)
        const float* xp = x + (((n * IN_CH + ic4 * 4) * HW + srow) * HW + w4 * 4);
        f32x4 v[4];
        #pragma unroll
        for (int j = 0; j < 4; ++j)
            v[j] = *reinterpret_cast<const f32x4*>(xp + j * (HW * HW));
        #pragma unroll
        for (int j2 = 0; j2 < 4; ++j2) {
            int w = w4 * 4 + j2;
            uint2 pk;
            pk.x = cvt_pk_bf16(v[0][j2], v[1][j2]);
            pk.y = cvt_pk_bf16(v[2][j2], v[3][j2]);
            *reinterpret_cast<uint2*>(xsB + kh * ROWB + ((w * 128 + ic4 * 8) ^ swz(w))) = pk;
        }
    }
    __syncthreads();   // the ONLY barrier

    // wave roles: wr = oc quarter (32 rows), wc = w half (64 cols)
    int wr = wid >> 1, wc = wid & 1;
    int l31 = lane & 31, lhi = lane >> 5;
    int p = wr >> 1, m = wr & 1;

    // A chunk pointer (16B units): proven fragment order, quarter-selected.
    const bf16x8* Ab = reinterpret_cast<const bf16x8*>(Wl)
                     + p * (9 * 512) + m * 256 + lane;

    f32x16 acc[2];
    #pragma unroll
    for (int bq = 0; bq < 2; ++bq)
        #pragma unroll
        for (int r = 0; r < 16; ++r) acc[bq][r] = 0.0f;

    #pragma unroll
    for (int t = 0; t < 9; ++t) {
        // per-tap A fragments: 4 lane-contiguous 1KB dwordx4 loads from L2-resident Wl
        bf16x8 aCur[4];
        #pragma unroll
        for (int ks = 0; ks < 4; ++ks) aCur[ks] = Ab[t * 512 + ks * 64];

        int kh = t / 3, kw = t % 3;
        int xc0 = (wc * 64 + l31 + 8 * kw - 8) & 127;   // circular column
        int xc1 = (xc0 + 32) & 127;
        int b0base = kh * ROWB + xc0 * 128 + lhi * 16, s0 = swz(xc0);
        int b1base = kh * ROWB + xc1 * 128 + lhi * 16, s1 = swz(xc1);
        #pragma unroll
        for (int ks = 0; ks < 4; ++ks) {   // K=16 per MFMA, 64 ic per tap
            bf16x8 b0 = *reinterpret_cast<const bf16x8*>(xsB + ((b0base + ks * 32) ^ s0));
            bf16x8 b1 = *reinterpret_cast<const bf16x8*>(xsB + ((b1base + ks * 32) ^ s1));
            acc[0] = __builtin_amdgcn_mfma_f32_32x32x16_bf16(aCur[ks], b0, acc[0], 0, 0, 0);
            acc[1] = __builtin_amdgcn_mfma_f32_32x32x16_bf16(aCur[ks], b1, acc[1], 0, 0, 0);
        }
    }

    // ---- epilogue: bias + store. D: col=l31(w), row=(reg&3)+8*(reg>>2)+4*lhi ----
    int outbase = (n * OUT_CH) * HW * HW + h * HW;
    #pragma unroll
    for (int bq = 0; bq < 2; ++bq) {
        int wcol = wc * 64 + bq * 32 + l31;
        #pragma unroll
        for (int reg = 0; reg < 16; ++reg) {
            int oc = wr * 32 + (reg & 3) + 8 * (reg >> 2) + 4 * lhi;
            y[outbase + oc * HW * HW + wcol] = acc[bq][reg] + bias[oc];
        }
    }
}

extern "C" void kernel_launch(void* const* d_in, const int* in_sizes, int n_in,
                              void* d_out, int out_size, void* d_ws, size_t ws_size,
                              hipStream_t stream) {
    const float* x = (const float*)d_in[0];
    const float* W = (const float*)d_in[1];
    const float* b = (const float*)d_in[2];
    float* y = (float*)d_out;

    unsigned short* Wl = (unsigned short*)d_ws;   // 147456 B

    hipLaunchKernelGGL(wprep_kernel, dim3((OUT_CH * IN_CH * KTAPS + 255) / 256), dim3(256), 0, stream, W, Wl);
    hipLaunchKernelGGL(conv_kernel_f, dim3(16 * HW), dim3(512), 0, stream, x, Wl, b, y);
}

// Round 11
// 62.418 us; speedup vs baseline: 1.0966x; 1.0204x over previous
//
#include <hip/hip_runtime.h>

#define IN_CH 64
#define OUT_CH 128
#define HW 128
#define KTAPS 9
#define ROWB 16384             // bytes per staged row image: 128 w * 64 ic * 2B

typedef __bf16 bf16x8 __attribute__((ext_vector_type(8)));
typedef float f32x16 __attribute__((ext_vector_type(16)));
typedef float f32x4 __attribute__((ext_vector_type(4)));

// fp32 -> bf16 round-to-nearest-even (data has no NaN/Inf) — prep use
__device__ __forceinline__ unsigned f2bf(float f) {
    unsigned u = __builtin_bit_cast(unsigned, f);
    return (u + 0x7FFFu + ((u >> 16) & 1u)) >> 16;
}

// HW packed f32x2 -> bf16x2 (RNE), 1 instruction (no builtin on gfx950)
__device__ __forceinline__ unsigned cvt_pk_bf16(float lo, float hi) {
    unsigned r;
    asm("v_cvt_pk_bf16_f32 %0, %1, %2" : "=v"(r) : "v"(lo), "v"(hi));
    return r;   // [15:0]=bf16(lo), [31:16]=bf16(hi)
}

// 16B-granule XOR swizzle keyed by row (3 bits -> byte-addr bits 4..6).
// Reads and writes both land at the wave-access bank floor (verified R10 math).
__device__ __forceinline__ int swz(int r) { return ((r ^ (r >> 3)) & 7) << 4; }

// W (OIHW fp32) -> Wl in wave-fragment order (PROVEN since R6):
// 16B chunk index = (p*9 + t)*512 + (m*4 + ks)*64 + lane
// Chunk content: 8 bf16 of A[oc = p*64+m*32+(lane&31)][ic = ks*16+(lane>>5)*8 .. +8].
__global__ void wprep_kernel(const float* __restrict__ W, unsigned short* __restrict__ Wl) {
    int i = blockIdx.x * blockDim.x + threadIdx.x;   // 73728 bf16 elements
    if (i >= OUT_CH * IN_CH * KTAPS) return;
    int p  = i / 36864;
    int r  = i % 36864;
    int t  = r >> 12;          // 0..8
    int r2 = r & 4095;
    int m  = r2 >> 11;
    int ks = (r2 >> 9) & 3;
    int l  = (r2 >> 3) & 63;
    int e  = r2 & 7;
    int oc = p * 64 + m * 32 + (l & 31);
    int ic = ks * 16 + (l >> 5) * 8 + e;
    int kh = t / 3, kw = t % 3;
    Wl[i] = (unsigned short)f2bf(W[((oc * IN_CH + ic) * 3 + kh) * 3 + kw]);
}

// Fused conv, 512 threads / 8 waves per (n,h) block; each wave a 32oc x 64w
// tile (acc 32 VGPR). launch_bounds(512,5): ~102-reg cap gives the scheduler
// room for the named even/odd A double-buffer (one-tap-ahead L2 prefetch).
__global__ __launch_bounds__(512, 5) void conv_kernel_f(
    const float* __restrict__ x, const unsigned short* __restrict__ Wl,
    const float* __restrict__ bias, float* __restrict__ y)
{
    __shared__ __align__(16) unsigned char xsB[3 * ROWB];   // 48 KiB -> 3 blocks/CU

    int bid = blockIdx.x;
    int sb  = (bid & 7) * 256 + (bid >> 3);   // XCD-contiguous h ranges (bijective: 2048 = 8*256)
    int n = sb >> 7, h = sb & 127;
    int tid = threadIdx.x;
    int wid = tid >> 6, lane = tid & 63;

    // ---- stage 3 B-rows (h-8, h, h+8): 1536 quarter-groups (kh, ic4, w4),
    //      exactly 3 per thread; per group 4 float4 loads -> 8 cvt_pk -> 4 b64 writes.
    #pragma unroll
    for (int g = 0; g < 3; ++g) {
        int q   = g * 512 + tid;     // 0..1535
        int w4  = q & 31;
        int ic4 = (q >> 5) & 15;
        int kh  = q >> 9;
        int srow = (h + kh * 8 + 120) & 127;   // h-8, h, h+8 (mod 128)
        const float* xp = x + (((n * IN_CH + ic4 * 4) * HW + srow) * HW + w4 * 4);
        f32x4 v[4];
        #pragma unroll
        for (int j = 0; j < 4; ++j)
            v[j] = *reinterpret_cast<const f32x4*>(xp + j * (HW * HW));
        #pragma unroll
        for (int j2 = 0; j2 < 4; ++j2) {
            int w = w4 * 4 + j2;
            uint2 pk;
            pk.x = cvt_pk_bf16(v[0][j2], v[1][j2]);
            pk.y = cvt_pk_bf16(v[2][j2], v[3][j2]);
            *reinterpret_cast<uint2*>(xsB + kh * ROWB + ((w * 128 + ic4 * 8) ^ swz(w))) = pk;
        }
    }
    __syncthreads();   // the ONLY barrier

    // wave roles: wr = oc quarter (32 rows), wc = w half (64 cols)
    int wr = wid >> 1, wc = wid & 1;
    int l31 = lane & 31, lhi = lane >> 5;
    int p = wr >> 1, m = wr & 1;

    // A chunk pointer (16B units): proven fragment order, quarter-selected.
    const bf16x8* Ab = reinterpret_cast<const bf16x8*>(Wl)
                     + p * (9 * 512) + m * 256 + lane;

    f32x16 acc[2];
    #pragma unroll
    for (int bq = 0; bq < 2; ++bq)
        #pragma unroll
        for (int r = 0; r < 16; ++r) acc[bq][r] = 0.0f;

    // ---- K-loop: named even/odd A buffers, one-tap-ahead prefetch ----
    bf16x8 aE[4], aO[4];
    auto LOAD_A = [&](bf16x8* dst, int t) {
        #pragma unroll
        for (int ks = 0; ks < 4; ++ks) dst[ks] = Ab[t * 512 + ks * 64];
    };
    auto TAP = [&](const bf16x8* a, int t) {
        int kh = t / 3, kw = t % 3;                      // compile-time after unroll
        int xc0 = (wc * 64 + l31 + 8 * kw - 8) & 127;    // circular column
        int xc1 = (xc0 + 32) & 127;
        int b0base = kh * ROWB + xc0 * 128 + lhi * 16, s0 = swz(xc0);
        int b1base = kh * ROWB + xc1 * 128 + lhi * 16, s1 = swz(xc1);
        #pragma unroll
        for (int ks = 0; ks < 4; ++ks) {   // K=16 per MFMA, 64 ic per tap
            bf16x8 b0 = *reinterpret_cast<const bf16x8*>(xsB + ((b0base + ks * 32) ^ s0));
            bf16x8 b1 = *reinterpret_cast<const bf16x8*>(xsB + ((b1base + ks * 32) ^ s1));
            acc[0] = __builtin_amdgcn_mfma_f32_32x32x16_bf16(a[ks], b0, acc[0], 0, 0, 0);
            acc[1] = __builtin_amdgcn_mfma_f32_32x32x16_bf16(a[ks], b1, acc[1], 0, 0, 0);
        }
    };

    LOAD_A(aE, 0);
    #pragma unroll
    for (int tp = 0; tp < 4; ++tp) {       // taps (2tp, 2tp+1)
        LOAD_A(aO, 2 * tp + 1);            // prefetch odd tap
        TAP(aE, 2 * tp);
        LOAD_A(aE, 2 * tp + 2);            // prefetch next even tap (t=8 at tp=3)
        TAP(aO, 2 * tp + 1);
    }
    TAP(aE, 8);

    // ---- epilogue: bias + store. D: col=l31(w), row=(reg&3)+8*(reg>>2)+4*lhi ----
    int outbase = (n * OUT_CH) * HW * HW + h * HW;
    #pragma unroll
    for (int bq = 0; bq < 2; ++bq) {
        int wcol = wc * 64 + bq * 32 + l31;
        #pragma unroll
        for (int reg = 0; reg < 16; ++reg) {
            int oc = wr * 32 + (reg & 3) + 8 * (reg >> 2) + 4 * lhi;
            y[outbase + oc * HW * HW + wcol] = acc[bq][reg] + bias[oc];
        }
    }
}

extern "C" void kernel_launch(void* const* d_in, const int* in_sizes, int n_in,
                              void* d_out, int out_size, void* d_ws, size_t ws_size,
                              hipStream_t stream) {
    const float* x = (const float*)d_in[0];
    const float* W = (const float*)d_in[1];
    const float* b = (const float*)d_in[2];
    float* y = (float*)d_out;

    unsigned short* Wl = (unsigned short*)d_ws;   // 147456 B

    hipLaunchKernelGGL(wprep_kernel, dim3((OUT_CH * IN_CH * KTAPS + 255) / 256), dim3(256), 0, stream, W, Wl);
    hipLaunchKernelGGL(conv_kernel_f, dim3(16 * HW), dim3(512), 0, stream, x, Wl, b, y);
}